// Round 7
// baseline (618.995 us; speedup 1.0000x reference)
//
#include <hip/hip_runtime.h>
#include <cstdint>

#define BTOT 65536
#define NA 4096
#define NS 16
#define DD 128
#define SCALE 0.08838834764831845f

typedef __attribute__((ext_vector_type(4))) float f32x4;
typedef __attribute__((ext_vector_type(2))) float f32x2;

__device__ __forceinline__ unsigned short f2bf(float f) {
  unsigned u = __float_as_uint(f);
  return (unsigned short)((u + 0x7fffu + ((u >> 16) & 1u)) >> 16);
}
__device__ __forceinline__ float bf2f(unsigned short s) {
  return __uint_as_float(((unsigned)s) << 16);
}
__device__ __forceinline__ float sigm(float x) { return 1.0f / (1.0f + expf(-x)); }

__device__ __forceinline__ float red32(float v) {
  v += __shfl_xor(v, 1); v += __shfl_xor(v, 2); v += __shfl_xor(v, 4);
  v += __shfl_xor(v, 8); v += __shfl_xor(v, 16);
  return v;
}
__device__ __forceinline__ float red16(float v) {
  v += __shfl_xor(v, 1); v += __shfl_xor(v, 2);
  v += __shfl_xor(v, 4); v += __shfl_xor(v, 8);
  return v;
}

// ---- VALU GEMM core: 32 rows x 128 cols, out = X(32x128) @ W(128x128)^T ----
// Thread t: rows rg+8i (rg=t>>5), cols p*64 + cl + 32j (cl=t&31). acc[i][p*2+j].
__device__ __forceinline__ void vgemm32(const float* W, const float (*Xl)[132], float (*Wl)[132],
                                        float acc[4][4], int t) {
  int rg = t >> 5, cl = t & 31;
#pragma unroll
  for (int p = 0; p < 2; ++p) {
    __syncthreads();
    for (int idx = t; idx < 64 * DD; idx += 256) Wl[idx >> 7][idx & 127] = W[p * 64 * DD + idx];
    __syncthreads();
    for (int k = 0; k < DD; k += 4) {
      f32x4 xv[4], wv[2];
#pragma unroll
      for (int i = 0; i < 4; ++i) xv[i] = *(const f32x4*)&Xl[rg + 8 * i][k];
#pragma unroll
      for (int j = 0; j < 2; ++j) wv[j] = *(const f32x4*)&Wl[cl + 32 * j][k];
#pragma unroll
      for (int i = 0; i < 4; ++i)
#pragma unroll
        for (int j = 0; j < 2; ++j) {
          float s = acc[i][p * 2 + j];
          s = fmaf(xv[i][0], wv[j][0], s);
          s = fmaf(xv[i][1], wv[j][1], s);
          s = fmaf(xv[i][2], wv[j][2], s);
          s = fmaf(xv[i][3], wv[j][3], s);
          acc[i][p * 2 + j] = s;
        }
    }
  }
}

__device__ __forceinline__ void zacc(float acc[4][4]) {
#pragma unroll
  for (int i = 0; i < 4; ++i)
#pragma unroll
    for (int j = 0; j < 4; ++j) acc[i][j] = 0.f;
}

// ---- counting sort of rows by agent (WRITE path) ----
__global__ __launch_bounds__(256) void k_count(const int* aidx, unsigned* counts) {
  int i = blockIdx.x * 256 + threadIdx.x;
  if (i < BTOT) atomicAdd(&counts[aidx[i]], 1u);
}

__global__ __launch_bounds__(256) void k_scan(const unsigned* counts, unsigned* offs) {
  __shared__ unsigned part[256];
  int t = threadIdx.x;
  unsigned local[16];
  unsigned s = 0;
#pragma unroll
  for (int j = 0; j < 16; ++j) { local[j] = counts[t * 16 + j]; s += local[j]; }
  part[t] = s;
  __syncthreads();
  for (int off = 1; off < 256; off <<= 1) {
    unsigned v = (t >= off) ? part[t - off] : 0u;
    __syncthreads();
    part[t] += v;
    __syncthreads();
  }
  unsigned excl = part[t] - s;
#pragma unroll
  for (int j = 0; j < 16; ++j) { offs[t * 16 + j] = excl; excl += local[j]; }
}

__global__ __launch_bounds__(256) void k_scatter(const int* aidx, const unsigned* offs, unsigned* cursor, unsigned* sorted) {
  int i = blockIdx.x * 256 + threadIdx.x;
  if (i < BTOT) {
    int a = aidx[i];
    unsigned pos = atomicAdd(&cursor[a], 1u);
    sorted[offs[a] + pos] = (unsigned)i;
  }
}

// ---- read projection: qn_r = l2norm(queries @ Wq^T + bq) -> bf16 ws ----
__global__ __launch_bounds__(256) void vgemm_read(const float* X, const float* Wq, const float* bq,
                                                  unsigned short* qn_out) {
  __shared__ float Xl[32][132];
  __shared__ float Wl[64][132];
  int t = threadIdx.x;
  int r0 = blockIdx.x * 32;
  for (int idx = t; idx < 32 * DD; idx += 256) Xl[idx >> 7][idx & 127] = X[(size_t)r0 * DD + idx];
  float acc[4][4];
  zacc(acc);
  vgemm32(Wq, Xl, Wl, acc, t);  // first internal sync covers Xl staging
  int rg = t >> 5, cl = t & 31;
#pragma unroll
  for (int i = 0; i < 4; ++i) {
    float v[4], ss = 0;
#pragma unroll
    for (int pj = 0; pj < 4; ++pj) {
      int col = (pj >> 1) * 64 + cl + 32 * (pj & 1);
      v[pj] = acc[i][pj] + bq[col];
      ss += v[pj] * v[pj];
    }
    ss = red32(ss);
    float inv = 1.0f / fmaxf(sqrtf(ss), 1e-12f);
#pragma unroll
    for (int pj = 0; pj < 4; ++pj) {
      int col = (pj >> 1) * 64 + cl + 32 * (pj & 1);
      qn_out[(size_t)(r0 + rg + 8 * i) * DD + col] = f2bf(v[pj] * inv);
    }
  }
}

// ---- SORT-FREE per-row read: one wave per row, direct gather of memory[aidx[b]] ----
__global__ __launch_bounds__(256) void k_rowread(const float* mem, const int* aidx,
                                                 const unsigned short* qn_r, unsigned short* readv) {
  int w = threadIdx.x >> 6, lane = threadIdx.x & 63;
  int b = blockIdx.x * 4 + w;
  int a = aidx[b];
  const float* mg = mem + (size_t)a * (NS * DD);
  unsigned qu = *(const unsigned*)(qn_r + (size_t)b * DD + 2 * lane);
  float q0 = bf2f((unsigned short)(qu & 0xffffu));
  float q1 = bf2f((unsigned short)(qu >> 16));
  float mm0[NS], mm1[NS], sc[NS];
#pragma unroll
  for (int s = 0; s < NS; ++s) {
    f32x2 mv = *(const f32x2*)(mg + s * DD + 2 * lane);
    mm0[s] = mv[0];
    mm1[s] = mv[1];
    float pn = mv[0] * mv[0] + mv[1] * mv[1];
    float pd = q0 * mv[0] + q1 * mv[1];
#pragma unroll
    for (int msk = 1; msk <= 32; msk <<= 1) {
      pn += __shfl_xor(pn, msk);
      pd += __shfl_xor(pd, msk);
    }
    sc[s] = pd / fmaxf(sqrtf(pn), 1e-12f) * SCALE;
  }
  float mx = sc[0];
#pragma unroll
  for (int s = 1; s < NS; ++s) mx = fmaxf(mx, sc[s]);
  float wv[NS], sum = 0;
#pragma unroll
  for (int s = 0; s < NS; ++s) { wv[s] = expf(sc[s] - mx); sum += wv[s]; }
  float rs = 1.0f / sum;
  float r0a = 0, r1a = 0;
#pragma unroll
  for (int s = 0; s < NS; ++s) { r0a += wv[s] * mm0[s]; r1a += wv[s] * mm1[s]; }
  r0a *= rs;
  r1a *= rs;
  unsigned outp = (unsigned)f2bf(r0a) | ((unsigned)f2bf(r1a) << 16);
  *(unsigned*)(readv + (size_t)b * DD + 2 * lane) = outp;
}

// ---- write projections: qn_w, ei = sigmoid(We x+be)*inten, ai = tanh(Wa x+ba)*inten ----
__global__ __launch_bounds__(256) void vgemm_write(const float* X, const float* Wq, const float* We,
                                                   const float* Wa, const float* bq, const float* be,
                                                   const float* ba, const float* Wg, const float* bg,
                                                   unsigned short* qn_w, unsigned short* ei, unsigned short* ai) {
  __shared__ float Xl[32][132];
  __shared__ float Wl[64][132];
  int t = threadIdx.x;
  int r0 = blockIdx.x * 32;
  for (int idx = t; idx < 32 * DD; idx += 256) Xl[idx >> 7][idx & 127] = X[(size_t)r0 * DD + idx];
  __syncthreads();
  int rg = t >> 5, cl = t & 31;
  float inten[4];
#pragma unroll
  for (int i = 0; i < 4; ++i) {
    float d = 0;
#pragma unroll
    for (int m = 0; m < 4; ++m) d += Xl[rg + 8 * i][cl * 4 + m] * Wg[cl * 4 + m];
    d = red32(d);
    inten[i] = sigm(d + bg[0]);
  }
  float acc[4][4];
  // pass 1: Wq -> l2norm -> qn_w
  zacc(acc);
  vgemm32(Wq, Xl, Wl, acc, t);
#pragma unroll
  for (int i = 0; i < 4; ++i) {
    float v[4], ss = 0;
#pragma unroll
    for (int pj = 0; pj < 4; ++pj) {
      int col = (pj >> 1) * 64 + cl + 32 * (pj & 1);
      v[pj] = acc[i][pj] + bq[col];
      ss += v[pj] * v[pj];
    }
    ss = red32(ss);
    float inv = 1.0f / fmaxf(sqrtf(ss), 1e-12f);
#pragma unroll
    for (int pj = 0; pj < 4; ++pj) {
      int col = (pj >> 1) * 64 + cl + 32 * (pj & 1);
      qn_w[(size_t)(r0 + rg + 8 * i) * DD + col] = f2bf(v[pj] * inv);
    }
  }
  // pass 2: We -> sigmoid * inten -> ei
  zacc(acc);
  vgemm32(We, Xl, Wl, acc, t);
#pragma unroll
  for (int i = 0; i < 4; ++i)
#pragma unroll
    for (int pj = 0; pj < 4; ++pj) {
      int col = (pj >> 1) * 64 + cl + 32 * (pj & 1);
      float x = acc[i][pj] + be[col];
      ei[(size_t)(r0 + rg + 8 * i) * DD + col] = f2bf(sigm(x) * inten[i]);
    }
  // pass 3: Wa -> tanh * inten -> ai
  zacc(acc);
  vgemm32(Wa, Xl, Wl, acc, t);
#pragma unroll
  for (int i = 0; i < 4; ++i)
#pragma unroll
    for (int pj = 0; pj < 4; ++pj) {
      int col = (pj >> 1) * 64 + cl + 32 * (pj & 1);
      float x = acc[i][pj] + ba[col];
      ai[(size_t)(r0 + rg + 8 * i) * DD + col] = f2bf(tanhf(x) * inten[i]);
    }
}

// ---- per-agent WRITE: scores -> softmax -> outer-product accumulate -> finalize (f32 out) ----
__global__ __launch_bounds__(256, 2) void k_agent_write(const float* mem, const unsigned* counts,
                                                        const unsigned* offs, const unsigned* sorted,
                                                        const unsigned short* qn_w, const unsigned short* ei,
                                                        const unsigned short* ai, float* out_mem) {
  int a = blockIdx.x, t = threadIdx.x;
  const float* mg = mem + (size_t)a * (NS * DD);
  unsigned cnt = counts[a];
  if (cnt == 0) {
    for (int i = t; i < NS * DD; i += 256) out_mem[(size_t)a * (NS * DD) + i] = mg[i];
    return;
  }
  __shared__ float mld[NS][132];
  __shared__ float qld[DD];
  __shared__ float invn[NS];
  __shared__ float scl[NS];
  __shared__ float wls[NS];
  __shared__ float n2c[4][8];

  for (int i = t; i < NS * DD; i += 256) mld[i >> 7][i & 127] = mg[i];
  __syncthreads();
  int s_ = t >> 4, dq = t & 15;
  {
    float pn = 0;
#pragma unroll
    for (int i = 0; i < 8; ++i) { float m = mld[s_][dq * 8 + i]; pn += m * m; }
    pn = red16(pn);
    if (dq == 0) invn[s_] = 1.0f / fmaxf(sqrtf(pn), 1e-12f);
  }
  __syncthreads();
  unsigned base = offs[a];
  int dcol = t & 127, h = t >> 7;
  float Eacc[8], Aacc[8];
#pragma unroll
  for (int j = 0; j < 8; ++j) { Eacc[j] = 0; Aacc[j] = 0; }
  for (unsigned r = 0; r < cnt; ++r) {
    unsigned b = sorted[base + r];
    if (t < DD) qld[t] = bf2f(qn_w[(size_t)b * DD + t]);
    __syncthreads();
    float sp = 0;
#pragma unroll
    for (int i = 0; i < 8; ++i) sp += qld[dq * 8 + i] * mld[s_][dq * 8 + i];
    sp = red16(sp);
    if (dq == 0) scl[s_] = sp * invn[s_] * SCALE;
    __syncthreads();
    float mx = scl[0];
#pragma unroll
    for (int j = 1; j < NS; ++j) mx = fmaxf(mx, scl[j]);
    if (dq == 0) wls[s_] = expf(scl[s_] - mx);
    __syncthreads();
    float sum = 0;
#pragma unroll
    for (int j = 0; j < NS; ++j) sum += wls[j];
    float rs = 1.0f / sum;
    float ev = bf2f(ei[(size_t)b * DD + dcol]);
    float av = bf2f(ai[(size_t)b * DD + dcol]);
#pragma unroll
    for (int j = 0; j < 8; ++j) {
      float wv = wls[h * 8 + j] * rs;
      Eacc[j] += wv * ev;
      Aacc[j] += wv * av;
    }
    __syncthreads();
  }
  float nsv[8], q2[8];
#pragma unroll
  for (int j = 0; j < 8; ++j) {
    int ss = h * 8 + j;
    float m = mld[ss][dcol];
    float ns = m * (1.0f - Eacc[j]) + Aacc[j];
    nsv[j] = ns;
    q2[j] = ns * ns;
  }
#pragma unroll
  for (int msk = 1; msk <= 32; msk <<= 1) {
#pragma unroll
    for (int j = 0; j < 8; ++j) q2[j] += __shfl_xor(q2[j], msk);
  }
  int wid = t >> 6;
  if ((t & 63) == 0) {
#pragma unroll
    for (int j = 0; j < 8; ++j) n2c[wid][j] = q2[j];
  }
  __syncthreads();
#pragma unroll
  for (int j = 0; j < 8; ++j) {
    int ss = h * 8 + j;
    float tot = n2c[h * 2][j] + n2c[h * 2 + 1][j];
    float inv = 1.0f / fmaxf(sqrtf(tot), 1e-12f);
    out_mem[(size_t)a * (NS * DD) + ss * DD + dcol] = nsv[j] * inv;
  }
}

// ---- fused output: LN(gelu(readv @ Wf^T + bf)) * ln_g + ln_b  (f32 out) ----
__global__ __launch_bounds__(256) void vgemm_fused(const unsigned short* readv, const float* Wf,
                                                   const float* bf_, const float* ln_g, const float* ln_b,
                                                   float* outp) {
  __shared__ float Xl[32][132];
  __shared__ float Wl[64][132];
  int t = threadIdx.x;
  int r0 = blockIdx.x * 32;
  for (int idx = t; idx < 32 * DD; idx += 256) Xl[idx >> 7][idx & 127] = bf2f(readv[(size_t)r0 * DD + idx]);
  float acc[4][4];
  zacc(acc);
  vgemm32(Wf, Xl, Wl, acc, t);  // first internal sync covers Xl staging
  int rg = t >> 5, cl = t & 31;
#pragma unroll
  for (int i = 0; i < 4; ++i) {
    float g[4];
    float msum = 0;
#pragma unroll
    for (int pj = 0; pj < 4; ++pj) {
      int col = (pj >> 1) * 64 + cl + 32 * (pj & 1);
      float x = acc[i][pj] + bf_[col];
      g[pj] = 0.5f * x * (1.0f + erff(x * 0.70710678118654752f));
      msum += g[pj];
    }
    float m = red32(msum) * (1.0f / 128.0f);
    float qsum = 0;
#pragma unroll
    for (int pj = 0; pj < 4; ++pj) { float d = g[pj] - m; qsum += d * d; }
    float q = red32(qsum) * (1.0f / 128.0f);
    float rinv = 1.0f / sqrtf(q + 1e-5f);
#pragma unroll
    for (int pj = 0; pj < 4; ++pj) {
      int col = (pj >> 1) * 64 + cl + 32 * (pj & 1);
      float y = (g[pj] - m) * rinv * ln_g[col] + ln_b[col];
      outp[(size_t)(r0 + rg + 8 * i) * DD + col] = y;
    }
  }
}

extern "C" void kernel_launch(void* const* d_in, const int* in_sizes, int n_in,
                              void* d_out, int out_size, void* d_ws, size_t ws_size,
                              hipStream_t stream) {
  const float* queries  = (const float*)d_in[0];
  const float* wqueries = (const float*)d_in[1];
  const float* memory   = (const float*)d_in[2];
  const float* Wq = (const float*)d_in[3];
  const float* bq = (const float*)d_in[4];
  const float* We = (const float*)d_in[5];
  const float* be = (const float*)d_in[6];
  const float* Wa = (const float*)d_in[7];
  const float* ba = (const float*)d_in[8];
  const float* Wf = (const float*)d_in[9];
  const float* bf_ = (const float*)d_in[10];
  const float* ln_g = (const float*)d_in[11];
  const float* ln_b = (const float*)d_in[12];
  const float* Wg = (const float*)d_in[13];
  const float* bg = (const float*)d_in[14];
  const int* aidx = (const int*)d_in[15];

  const size_t REQUIRED = 442368 + 3ull * 16777216ull;  // 50,774,016 B
  if (ws_size < REQUIRED) {
    hipMemsetAsync(d_out, 0, (size_t)out_size * sizeof(float), stream);  // zeros signature 3.046875
    return;
  }

  char* ws = (char*)d_ws;
  unsigned* counts = (unsigned*)(ws + 131072);
  unsigned* cursor = (unsigned*)(ws + 147456);
  unsigned* offs   = (unsigned*)(ws + 163840);
  unsigned* sorted = (unsigned*)(ws + 180224);
  unsigned short* bufA = (unsigned short*)(ws + 442368);            // qn_r then qn_w
  unsigned short* bufB = (unsigned short*)(ws + 442368 + 16777216); // readv then ai
  unsigned short* bufC = (unsigned short*)(ws + 442368 + 33554432); // ei

  float* out_fused = (float*)d_out;                  // [65536,128] f32
  float* out_mem   = out_fused + (size_t)BTOT * DD;  // [4096,16,128] f32

  hipMemsetAsync(counts, 0, 32768, stream);  // counts + cursor
  k_count<<<BTOT / 256, 256, 0, stream>>>(aidx, counts);
  k_scan<<<1, 256, 0, stream>>>(counts, offs);
  k_scatter<<<BTOT / 256, 256, 0, stream>>>(aidx, offs, cursor, sorted);

  // READ path (sort-free)
  vgemm_read<<<BTOT / 32, 256, 0, stream>>>(queries, Wq, bq, bufA);
  k_rowread<<<BTOT / 4, 256, 0, stream>>>(memory, aidx, bufA, bufB);
  vgemm_fused<<<BTOT / 32, 256, 0, stream>>>(bufB, Wf, bf_, ln_g, ln_b, out_fused);

  // WRITE path (sorted-based)
  vgemm_write<<<BTOT / 32, 256, 0, stream>>>(wqueries, Wq, We, Wa, bq, be, ba, Wg, bg, bufA, bufC, bufB);
  k_agent_write<<<NA, 256, 0, stream>>>(memory, counts, offs, sorted, bufA, bufC, bufB, out_mem);
}